// Round 11
// baseline (363.551 us; speedup 1.0000x reference)
//
#include <hip/hip_runtime.h>
#include <hip/hip_bf16.h>
#include <type_traits>

constexpr int B_ = 8, C_ = 256, P_ = 64, H_ = 64, W_ = 64, HW_ = 4096;

typedef __attribute__((ext_vector_type(8))) short short8;   // 8 bf16
typedef __attribute__((ext_vector_type(4))) short short4v;  // 4 bf16 (8 B)
typedef __attribute__((ext_vector_type(4))) float f32x4;

__device__ __forceinline__ short bfbits(float f) {
    __hip_bfloat16 h = __float2bfloat16(f);
    return *reinterpret_cast<short*>(&h);
}
__device__ __forceinline__ float bf2f(short s) {
    __hip_bfloat16 h = *reinterpret_cast<__hip_bfloat16*>(&s);
    return (float)h;
}

// async global->LDS, 16B per lane; dst must be wave-uniform base (HW adds lane*16)
#define GLL16(gsrc, ldst)                                                      \
    __builtin_amdgcn_global_load_lds(                                         \
        (const __attribute__((address_space(1))) void*)(gsrc),                \
        (__attribute__((address_space(3))) void*)(ldst), 16, 0, 0)

// ---------------------------------------------------------------------------
// Fragment-linear packed layouts (one wave-load = base + lane*16, contiguous):
//   xtP/xcP [b][tile16][kc2][lane64]x16B : chunk = x[row=tile*16+lm][p=kc*32+lq*8..+8]
//   xbP     [b][g128][ct16][lane64]x16B  : chunk = xb[c=ct*16+lm][m=g*32+lq*8..+8]
//   wbP     [tap9][cb8][cot16][lane64]x16B: chunk = w[co=cot*16+lm][ci=cb*32+lq*8..+8]
//   w1P     [conv2][pt4][kc8][hl2][lane64]x16B: chunk = w[p=pt*16+lm][c=kc*32+lq*8..+8]
// ---------------------------------------------------------------------------

// K0: weight prep, fp32 OIHW -> fragment-linear bf16 wbP. 288 blocks.
__global__ __launch_bounds__(256) void k_prep_w(
    const float* __restrict__ w, short8* __restrict__ wbP)
{
    const int idx = blockIdx.x * 256 + threadIdx.x;      // < 9*8*16*64 = 73728
    const int lane = idx & 63, cot = (idx >> 6) & 15;
    const int cb = (idx >> 10) & 7, tap = idx >> 13;
    const int lm = lane & 15, lq = lane >> 4;
    const int co = cot * 16 + lm, ci0 = cb * 32 + lq * 8;
    short8 v;
#pragma unroll
    for (int k = 0; k < 8; ++k)
        v[k] = bfbits(w[(co * 256 + ci0 + k) * 9 + tap]);
    wbP[idx] = v;
}

// K0d: 1x1-conv weight prep: w_top/w_cen fp32 [64][256] -> hi/lo fragment-
// linear A-frags w1P. 16 blocks (4096 threads, one chunk-pair each).
__global__ __launch_bounds__(256) void k_prep_w1(
    const float* __restrict__ wt, const float* __restrict__ wc,
    short8* __restrict__ w1P)
{
    const int idx = blockIdx.x * 256 + threadIdx.x;      // < 4096
    const int lane = idx & 63, kc = (idx >> 6) & 7;
    const int pt = (idx >> 9) & 3, conv = idx >> 11;
    const int lm = lane & 15, lq = lane >> 4;
    const float* w = conv ? wc : wt;
    const float* wp = w + (pt * 16 + lm) * C_ + kc * 32 + lq * 8;
    short8 vh, vl;
#pragma unroll
    for (int k = 0; k < 8; ++k) {
        const float v = wp[k];
        const short h = bfbits(v);
        vh[k] = h;
        vl[k] = bfbits(v - bf2f(h));
    }
    const size_t o = (((size_t)(conv * 4 + pt) * 8 + kc) * 2) * 64 + lane;
    w1P[o] = vh;
    w1P[o + 64] = vl;
}

// K0c: fp32 [B][C][HW] -> bf16 same-order copy (conv3x3 staging input).
// 2048 blocks; thread: 4 float4 loads -> 2 short8 stores (16 elems).
__global__ __launch_bounds__(256) void k_cvt_bf16(
    const float* __restrict__ x, short8* __restrict__ xB)
{
    const size_t i = ((size_t)blockIdx.x * 256 + threadIdx.x) * 16;
    short8 o[2];
#pragma unroll
    for (int q = 0; q < 2; ++q) {
#pragma unroll
        for (int j = 0; j < 2; ++j) {
            const float4 v = *reinterpret_cast<const float4*>(&x[i + q * 8 + j * 4]);
            o[q][j * 4 + 0] = bfbits(v.x);
            o[q][j * 4 + 1] = bfbits(v.y);
            o[q][j * 4 + 2] = bfbits(v.z);
            o[q][j * 4 + 3] = bfbits(v.w);
        }
    }
    short8* dp = (short8*)&xB[i >> 3];
    dp[0] = o[0];
    dp[1] = o[1];
}

// K0b: xb [B][C][HW] bf16 -> fragment-linear xbP. 4096 blocks.
__global__ __launch_bounds__(256) void k_pack_xb(
    const __hip_bfloat16* __restrict__ xb, short8* __restrict__ xbP)
{
    const int tid = blockIdx.x * 256 + threadIdx.x;
    const int lane = tid & 63, wid = tid >> 6;           // wid < 8*128*16
    const int ct = wid & 15, g = (wid >> 4) & 127, b = wid >> 11;
    const int c = ct * 16 + (lane >> 2);
    const int mo = g * 32 + (lane & 3) * 8;
    const short8 v = *reinterpret_cast<const short8*>(
        &xb[((size_t)(b * 256 + c)) * HW_ + mo]);
    xbP[(size_t)wid * 64 + (lane & 3) * 16 + (lane >> 2)] = v;
}

// ---------------------------------------------------------------------------
// K1: 1x1 convs, R15 MFMA implementation (unchanged from R9).
// ---------------------------------------------------------------------------
__global__ __launch_bounds__(256) void k_conv1x1_mfma(
    const float* __restrict__ x, const short8* __restrict__ w1P,
    const float* __restrict__ b_top, const float* __restrict__ b_cen,
    short4v* __restrict__ xtPh, short4v* __restrict__ xtPl,
    short4v* __restrict__ xcPh, short4v* __restrict__ xcPl)
{
    const int b = blockIdx.y;
    const int t = threadIdx.x, wv = t >> 6, lane = t & 63;
    const int lm = lane & 15, lq = lane >> 4;
    const int nt = blockIdx.x * 4 + wv;
    const float* xp = x + (size_t)b * C_ * HW_ + nt * 16 + lm;

    f32x4 acc[2][4];   // [conv][p-tile]
#pragma unroll
    for (int i = 0; i < 2; ++i)
#pragma unroll
        for (int j = 0; j < 4; ++j) acc[i][j] = f32x4{0.f, 0.f, 0.f, 0.f};

    for (int kc = 0; kc < 8; ++kc) {
        // B-frag: lane = x[c = kc*32+lq*8 .. +8][n = nt*16+lm], hi/lo in-reg
        short8 bh, bl;
#pragma unroll
        for (int k = 0; k < 8; ++k) {
            const float v = xp[(size_t)(kc * 32 + lq * 8 + k) * HW_];
            const short h = bfbits(v);
            bh[k] = h;
            bl[k] = bfbits(v - bf2f(h));
        }
#pragma unroll
        for (int conv = 0; conv < 2; ++conv)
#pragma unroll
            for (int pt = 0; pt < 4; ++pt) {
                const size_t o =
                    (((size_t)(conv * 4 + pt) * 8 + kc) * 2) * 64 + lane;
                const short8 ah = w1P[o];
                const short8 al = w1P[o + 64];
                f32x4 a = acc[conv][pt];
                a = __builtin_amdgcn_mfma_f32_16x16x32_bf16(ah, bh, a, 0, 0, 0);
                a = __builtin_amdgcn_mfma_f32_16x16x32_bf16(ah, bl, a, 0, 0, 0);
                a = __builtin_amdgcn_mfma_f32_16x16x32_bf16(al, bh, a, 0, 0, 0);
                acc[conv][pt] = a;
            }
    }

    // Epilogue: D lane (lm,lq) holds p = pt*16 + lq*4 + r, n = nt*16 + lm.
    // Fragment target: kc = pt>>1, tl = (pt&1)*2 + (lq>>1), shortoff = (lq&1)*4.
#pragma unroll
    for (int conv = 0; conv < 2; ++conv) {
        const float* bias = conv ? b_cen : b_top;
        short4v* oh = conv ? xcPh : xtPh;
        short4v* ol = conv ? xcPl : xtPl;
#pragma unroll
        for (int pt = 0; pt < 4; ++pt) {
            const int kc = pt >> 1;
            const int tl = (pt & 1) * 2 + (lq >> 1);
            const size_t c16 = ((size_t)(b * 256 + nt) * 2 + kc) * 64 + tl * 16 + lm;
            short4v vh, vl;
#pragma unroll
            for (int r = 0; r < 4; ++r) {
                const float v = acc[conv][pt][r] + bias[pt * 16 + lq * 4 + r];
                const short h = bfbits(v);
                vh[r] = h;
                vl[r] = bfbits(v - bf2f(h));
            }
            oh[c16 * 2 + (lq & 1)] = vh;
            ol[c16 * 2 + (lq & 1)] = vl;
        }
    }
}

// ---------------------------------------------------------------------------
// K2/K5: 3x3 conv as implicit GEMM, bf16 MFMA. R16 h-pair structure
// (unchanged from R10): 1024 threads / 16 waves, 128 n x 256 co per block,
// grid 256 1D with b==XCD.
// ---------------------------------------------------------------------------
template <typename OT>
__global__ __launch_bounds__(1024, 4) void k_conv3x3_mfma(
    const short* __restrict__ xin, const short8* __restrict__ wbP,
    const float* __restrict__ bias, OT* __restrict__ out)
{
    __shared__ __align__(16) short Xs[4][66][40];
    const int lin = blockIdx.x;                 // 0..255
    const int b = lin & 7, hp = lin >> 3;       // b == XCD; hp = h-pair 0..31
    const int t = threadIdx.x;
    const int wave = t >> 6, lane = t & 63;
    const int lm = lane & 15, lq = lane >> 4;
    const int nq = wave >> 3, ch = wave & 7;    // row-half x co-pair

    f32x4 acc[4][2];   // [w_tile][co_tile]
#pragma unroll
    for (int i = 0; i < 4; ++i)
#pragma unroll
        for (int j = 0; j < 2; ++j) acc[i][j] = f32x4{0.f, 0.f, 0.f, 0.f};

    if (t < 256) {   // zero w-halo columns once (4 r x 2 sides x 32 ci)
        const int r = t >> 6, cc = t & 31, side = (t >> 5) & 1;
        Xs[r][side ? 65 : 0][cc] = 0;
    }

    const short* xbase = xin + (size_t)b * C_ * HW_;

    for (int cb = 0; cb < 8; ++cb) {
        const int ci0 = cb * 32;
        __syncthreads();
        // stage 4 rows x 32 ci x 64 w: 2048 short4 over 1024 threads.
#pragma unroll
        for (int it = 0; it < 2; ++it) {
            const int idx = it * 1024 + t;
            const int r = idx >> 9, ci = (idx >> 4) & 31, wq = idx & 15;
            const int hh = hp * 2 + r - 1;
            short4v v = {0, 0, 0, 0};
            if (hh >= 0 && hh < H_)
                v = *reinterpret_cast<const short4v*>(
                    &xbase[(size_t)(ci0 + ci) * HW_ + hh * W_ + wq * 4]);
            Xs[r][1 + wq * 4 + 0][ci] = v[0];
            Xs[r][1 + wq * 4 + 1][ci] = v[1];
            Xs[r][1 + wq * 4 + 2][ci] = v[2];
            Xs[r][1 + wq * 4 + 3][ci] = v[3];
        }
        __syncthreads();

#pragma unroll 3
        for (int tap = 0; tap < 9; ++tap) {
            const int dh = tap / 3;
            const int dw = tap % 3;
            const int slot = nq + dh;           // wave's input row for this tap
            const short8* wp = wbP + ((size_t)(tap * 8 + cb)) * 1024 + lane;
            short8 af[2];
            af[0] = wp[(ch * 2 + 0) * 64];
            af[1] = wp[(ch * 2 + 1) * 64];
            short8 bf[4];
#pragma unroll
            for (int wt = 0; wt < 4; ++wt)
                bf[wt] = *reinterpret_cast<const short8*>(
                    &Xs[slot][wt * 16 + lm + dw][lq * 8]);
#pragma unroll
            for (int wt = 0; wt < 4; ++wt)
#pragma unroll
                for (int ct = 0; ct < 2; ++ct)
                    acc[wt][ct] = __builtin_amdgcn_mfma_f32_16x16x32_bf16(
                        af[ct], bf[wt], acc[wt][ct], 0, 0, 0);
        }
    }

#pragma unroll
    for (int wt = 0; wt < 4; ++wt) {
        const int pos = (hp * 2 + nq) * W_ + wt * 16 + lm;
#pragma unroll
        for (int ct = 0; ct < 2; ++ct) {
            const int co = ch * 32 + ct * 16 + lq * 4;
#pragma unroll
            for (int r = 0; r < 4; ++r) {
                const float v = acc[wt][ct][r] + bias[co + r];
                if constexpr (std::is_same<OT, __hip_bfloat16>::value)
                    out[((size_t)(b * C_ + co + r)) * HW_ + pos] = __float2bfloat16(v);
                else
                    out[((size_t)(b * C_ + co + r)) * HW_ + pos] = v;
            }
        }
    }
}

// ---------------------------------------------------------------------------
// K3: fused attention. R17: single barrier span per iteration — PV(mt)
// interleaved with S^T(mt+1) (T15 pattern). Double-buffered Ps (2x16KB);
// XB staged 1 ahead, XT 2 ahead (all waits a full iteration stale ->
// vmcnt(0) at top is ~free). Barriers 2/iter -> 1/iter; S^T's dependent
// 6-MFMA chains + exp/pack VALU hide under PV's 32 independent MFMAs.
// LDS 131.1 KB, 1 block/CU, 8 waves. b == XCD.
// Buffer liveness: XT[k]->buf k&1 (XT[mt] dead one iter before XT[mt+2]
// lands); XB[k]->buf k&1; Ps[k]->buf k&1. All rewrites barrier-protected.
// ---------------------------------------------------------------------------
__global__ __launch_bounds__(512, 2) void k_attn_mfma(
    const short8* __restrict__ xtPh, const short8* __restrict__ xtPl,
    const short8* __restrict__ xcPh, const short8* __restrict__ xcPl,
    const short8* __restrict__ xbP, float* __restrict__ O,
    float* __restrict__ Z)
{
    extern __shared__ __align__(16) char smem[];
    short8* XTs = (short8*)smem;                    // [2][1024]  (2 x 16 KB)
    short8* XBs = (short8*)(smem + 32768);          // [2][2048]  (2 x 32 KB)
    short8* Ps8 = (short8*)(smem + 98304);          // [2][8 T][2 mh][64] 32 KB
    short4v* Ps4 = (short4v*)(smem + 98304);
    float* zred = (float*)(smem + 131072);

    const int lin = blockIdx.x;                 // 0..255
    const int b = lin & 7, nblk = lin >> 3;     // b == XCD (round-robin dispatch)
    const int n0 = nblk * 128;

    const int t = threadIdx.x, wv = t >> 6, lane = t & 63;
    const int lm = lane & 15, lq = lane >> 4;
    const int mh = wv >> 2, nq2 = wv & 3;       // S^T split: m-half x n-quarter
    const int nq = wv >> 2, cq = wv & 3;        // PV split: n-half x c-quarter

    // Hoisted S^T B-frags: xc for wave's 2 n-tiles (nq2*2, nq2*2+1)
    short8 cB2[2][2][2];   // [ntile][kc][hilo]
#pragma unroll
    for (int ntile = 0; ntile < 2; ++ntile) {
        const int gt = nblk * 8 + nq2 * 2 + ntile;
        const size_t base = ((size_t)(b * 256 + gt) * 2) * 64 + lane;
        cB2[ntile][0][0] = xcPh[base];
        cB2[ntile][1][0] = xcPh[base + 64];
        cB2[ntile][0][1] = xcPl[base];
        cB2[ntile][1][1] = xcPl[base + 64];
    }
    asm volatile("s_waitcnt vmcnt(0)" ::: "memory");   // clean slate for counts

    auto stageXT = [&](int k) {                  // 2 chunks -> XT buf k&1
        short8* XT = XTs + (k & 1) * 1024;
        const size_t abase = ((size_t)(b * 512 + k * 8)) * 64;
#pragma unroll
        for (int j = 0; j < 2; ++j) {
            const int c = wv * 2 + j, ms = c >> 2, part = c & 3;
            const short8* src = (part < 2 ? xtPh : xtPl)
                                + abase + ms * 128 + (part & 1) * 64 + lane;
            GLL16(src, XT + c * 64);
        }
    };
    auto stageXB = [&](int k) {                  // 4 chunks -> XB buf k&1
        short8* XB = XBs + (k & 1) * 2048;
        const size_t p8 = ((size_t)(b * 2048 + k * 32)) * 64;
#pragma unroll
        for (int j = 0; j < 4; ++j) {
            const int e = j * 512 + wv * 64;
            GLL16(xbP + p8 + e + lane, XB + e);
        }
    };

    f32x4 acc[4][4];   // O partial [n-subtile within half][c-tile within quarter]
#pragma unroll
    for (int i = 0; i < 4; ++i)
#pragma unroll
        for (int jj = 0; jj < 4; ++jj) acc[i][jj] = f32x4{0.f, 0.f, 0.f, 0.f};
    float zp = 0.f;

    // S^T slice i (i = ms2*2 + ntile... i>>1 = ms2, i&1 = ntile) of tile k
    auto st_slice = [&](int k, int i) {
        const short8* XT = XTs + (k & 1) * 1024;
        const int stb = (k & 1) * 2048;          // Ps4 buffer offset
        const int ms2 = i >> 1, ntile = i & 1;
        const int ms = mh * 2 + ms2;
        const short8 aH0 = XT[(ms * 4 + 0) * 64 + lane];
        const short8 aH1 = XT[(ms * 4 + 1) * 64 + lane];
        const short8 aL0 = XT[(ms * 4 + 2) * 64 + lane];
        const short8 aL1 = XT[(ms * 4 + 3) * 64 + lane];
        f32x4 s = {0.f, 0.f, 0.f, 0.f};
        __builtin_amdgcn_s_setprio(1);
        s = __builtin_amdgcn_mfma_f32_16x16x32_bf16(aH0, cB2[ntile][0][0], s, 0, 0, 0);
        s = __builtin_amdgcn_mfma_f32_16x16x32_bf16(aH1, cB2[ntile][1][0], s, 0, 0, 0);
        s = __builtin_amdgcn_mfma_f32_16x16x32_bf16(aH0, cB2[ntile][0][1], s, 0, 0, 0);
        s = __builtin_amdgcn_mfma_f32_16x16x32_bf16(aH1, cB2[ntile][1][1], s, 0, 0, 0);
        s = __builtin_amdgcn_mfma_f32_16x16x32_bf16(aL0, cB2[ntile][0][0], s, 0, 0, 0);
        s = __builtin_amdgcn_mfma_f32_16x16x32_bf16(aL1, cB2[ntile][1][0], s, 0, 0, 0);
        __builtin_amdgcn_s_setprio(0);
        const float e0 = __expf(s[0]), e1 = __expf(s[1]);
        const float e2 = __expf(s[2]), e3 = __expf(s[3]);
        zp += (e0 + e1) + (e2 + e3);
        short4v pk = { bfbits(e0), bfbits(e1), bfbits(e2), bfbits(e3) };
        const int T = nq2 * 2 + ntile;
        const int lqp = (ms & 1) * 2 + (lq >> 1);
        Ps4[stb + (((T * 2 + mh) * 64) + lqp * 16 + lm) * 2 + (lq & 1)] = pk;
    };

    // PV chunk nt2 of tile mt (vb frags passed in)
    auto pv_chunk = [&](int mt, int nt2, const short8* vb0, const short8* vb1) {
        const int pvb = (mt & 1) * 1024;         // Ps8 buffer offset
        const int T = nq * 4 + nt2;
        const short8 pa0 = Ps8[pvb + (T * 2 + 0) * 64 + lane];
        const short8 pa1 = Ps8[pvb + (T * 2 + 1) * 64 + lane];
        __builtin_amdgcn_s_setprio(1);
#pragma unroll
        for (int q4 = 0; q4 < 4; ++q4) {
            acc[nt2][q4] = __builtin_amdgcn_mfma_f32_16x16x32_bf16(
                pa0, vb0[q4], acc[nt2][q4], 0, 0, 0);
            acc[nt2][q4] = __builtin_amdgcn_mfma_f32_16x16x32_bf16(
                pa1, vb1[q4], acc[nt2][q4], 0, 0, 0);
        }
        __builtin_amdgcn_s_setprio(0);
    };

    // ---- prologue: stage XT0, XB0, XT1; S^T(0) -> Ps[0] ----
    stageXT(0);
    stageXB(0);
    stageXT(1);
    asm volatile("s_waitcnt vmcnt(2)" ::: "memory");   // XT0+XB0 landed; XT1 in flight
    __builtin_amdgcn_sched_barrier(0);
    __builtin_amdgcn_s_barrier();
    __builtin_amdgcn_sched_barrier(0);
#pragma unroll
    for (int i = 0; i < 4; ++i) st_slice(0, i);
    asm volatile("s_waitcnt lgkmcnt(0)" ::: "memory"); // Ps[0] writes done
    __builtin_amdgcn_sched_barrier(0);

    // ---- main loop: iter mt does PV(mt) + S^T(mt+1), one barrier span ----
    for (int mt = 0; mt < 63; ++mt) {
        asm volatile("s_waitcnt vmcnt(0)" ::: "memory");  // all stale loads landed
        __builtin_amdgcn_sched_barrier(0);
        __builtin_amdgcn_s_barrier();          // Ps[mt] + XB[mt] + XT[mt+1] visible
        __builtin_amdgcn_sched_barrier(0);
        stageXB(mt + 1);                        // -> buf (mt+1)&1 (XB[mt-1] dead)
        if (mt < 62) stageXT(mt + 2);           // -> buf mt&1 (XT[mt] dead)

        // PV B-frags for this iter
        const short8* XB = XBs + (mt & 1) * 2048;
        short8 vb0[4], vb1[4];
#pragma unroll
        for (int q4 = 0; q4 < 4; ++q4) {
            const int ct = cq * 4 + q4;
            vb0[q4] = XB[ct * 64 + lane];
            vb1[q4] = XB[1024 + ct * 64 + lane];
        }
        // interleave: S^T slice i (latency-bound) + PV chunk i (throughput)
#pragma unroll
        for (int i = 0; i < 4; ++i) {
            st_slice(mt + 1, i);
            pv_chunk(mt, i, vb0, vb1);
        }
        asm volatile("s_waitcnt lgkmcnt(0)" ::: "memory");  // Ps[mt+1] writes done
        __builtin_amdgcn_sched_barrier(0);
    }

    // ---- epilogue: PV(63) ----
    asm volatile("s_waitcnt vmcnt(0)" ::: "memory");
    __builtin_amdgcn_sched_barrier(0);
    __builtin_amdgcn_s_barrier();
    __builtin_amdgcn_sched_barrier(0);
    {
        const short8* XB = XBs + (63 & 1) * 2048;
        short8 vb0[4], vb1[4];
#pragma unroll
        for (int q4 = 0; q4 < 4; ++q4) {
            const int ct = cq * 4 + q4;
            vb0[q4] = XB[ct * 64 + lane];
            vb1[q4] = XB[1024 + ct * 64 + lane];
        }
#pragma unroll
        for (int i = 0; i < 4; ++i) pv_chunk(63, i, vb0, vb1);
    }

    // Z: block reduction -> one atomicAdd
#pragma unroll
    for (int o = 32; o > 0; o >>= 1) zp += __shfl_down(zp, o, 64);
    if (lane == 0) zred[wv] = zp;
    __syncthreads();
    if (t == 0) {
        float zs = 0.f;
#pragma unroll
        for (int wvi = 0; wvi < 8; ++wvi) zs += zred[wvi];
        atomicAdd(&Z[b], zs);
    }

    // O direct stores (sole writer of this (b, n-stripe))
#pragma unroll
    for (int nt2 = 0; nt2 < 4; ++nt2) {
#pragma unroll
        for (int q4 = 0; q4 < 4; ++q4) {
            const int c = cq * 64 + q4 * 16 + lm;
#pragma unroll
            for (int r = 0; r < 4; ++r) {
                const int n = n0 + (nq * 4 + nt2) * 16 + lq * 4 + r;
                O[((size_t)b * HW_ + n) * C_ + c] = acc[nt2][q4][r];
            }
        }
    }
}

// ---------------------------------------------------------------------------
// K4: yB = bf16(x + O*(1/Z[b])) (flat reinterpretation add, bf16 output).
// ---------------------------------------------------------------------------
__global__ __launch_bounds__(256) void k_add_bf16(
    const float* __restrict__ x, const float* __restrict__ o,
    const float* __restrict__ Z, short4v* __restrict__ yB)
{
    const int bidx = blockIdx.x;
    const float invZ = 1.0f / Z[bidx >> 10];
    const size_t i = ((size_t)bidx * 256 + threadIdx.x) * 4;
    const float4 a = *reinterpret_cast<const float4*>(&x[i]);
    const float4 b = *reinterpret_cast<const float4*>(&o[i]);
    short4v r{bfbits(fmaf(b.x, invZ, a.x)), bfbits(fmaf(b.y, invZ, a.y)),
              bfbits(fmaf(b.z, invZ, a.z)), bfbits(fmaf(b.w, invZ, a.w))};
    yB[i >> 2] = r;
}

extern "C" void kernel_launch(void* const* d_in, const int* in_sizes, int n_in,
                              void* d_out, int out_size, void* d_ws, size_t ws_size,
                              hipStream_t stream)
{
    const float* x   = (const float*)d_in[0];
    const float* wt  = (const float*)d_in[1];
    const float* bt  = (const float*)d_in[2];
    const float* wc  = (const float*)d_in[3];
    const float* bc  = (const float*)d_in[4];
    const float* wbo = (const float*)d_in[5];
    const float* bbo = (const float*)d_in[6];
    const float* wo  = (const float*)d_in[7];
    const float* bo  = (const float*)d_in[8];
    float* out = (float*)d_out;

    uint8_t* w8 = (uint8_t*)d_ws;
    const size_t MB = 1u << 20;
    // [0,16): xtP/xcP (attn inputs; dead after attn)
    // [16,32): W1 (dead after conv1x1) -> xbB bf16 (conv3x3 out, dead after
    //          pack_xb) -> yB after attn
    // [32,48): xbP (dead after attn) -> Wb2 overlays after attn
    // [48,80): O (attn out); Wb1 at 48 (dead before attn); xB at [64,80)
    //          (read only by conv3x3 #1, which completes before attn writes O)
    short8* xtPh = (short8*)(w8);
    short8* xtPl = (short8*)(w8 + 4 * MB);
    short8* xcPh = (short8*)(w8 + 8 * MB);
    short8* xcPl = (short8*)(w8 + 12 * MB);
    short8* W1   = (short8*)(w8 + 16 * MB);   // 128 KB, dead after conv1x1
    __hip_bfloat16* xbB = (__hip_bfloat16*)(w8 + 16 * MB);
    short8* xbP  = (short8*)(w8 + 32 * MB);
    float*  O    = (float*)(w8 + 48 * MB);
    short8* Wb1  = (short8*)(w8 + 48 * MB);   // inside O region (dead before attn)
    short8* xB   = (short8*)(w8 + 64 * MB);   // bf16 x copy (conv3x3 #1 input)
    short8* Wb2  = (short8*)(w8 + 32 * MB);   // inside xbP region (dead after attn)
    short4v* yB  = (short4v*)(w8 + 16 * MB);  // bf16 residual sum (conv2 input)
    float*  Z    = (float*)(w8 + 80 * MB);

    hipMemsetAsync(Z, 0, B_ * sizeof(float), stream);
    k_prep_w<<<dim3(288), 256, 0, stream>>>(wbo, Wb1);
    k_prep_w1<<<dim3(16), 256, 0, stream>>>(wt, wc, W1);
    k_cvt_bf16<<<dim3(2048), 256, 0, stream>>>(x, xB);
    k_conv1x1_mfma<<<dim3(64, 8), 256, 0, stream>>>(
        x, W1, bt, bc, (short4v*)xtPh, (short4v*)xtPl,
        (short4v*)xcPh, (short4v*)xcPl);
    k_conv3x3_mfma<__hip_bfloat16><<<dim3(256), 1024, 0, stream>>>(
        (const short*)xB, Wb1, bbo, xbB);
    k_pack_xb<<<dim3(4096), 256, 0, stream>>>(xbB, xbP);
    k_attn_mfma<<<dim3(256), dim3(512), 131104, stream>>>(xtPh, xtPl, xcPh, xcPl,
                                                          xbP, O, Z);
    k_prep_w<<<dim3(288), 256, 0, stream>>>(wo, Wb2);
    k_add_bf16<<<dim3(8192), 256, 0, stream>>>(x, O, Z, yB);
    k_conv3x3_mfma<float><<<dim3(256), 1024, 0, stream>>>(
        (const short*)yB, Wb2, bo, out);
}